// Round 1
// baseline (1974.335 us; speedup 1.0000x reference)
//
#include <hip/hip_runtime.h>
#include <hip/hip_bf16.h>
#include <cstddef>

// CausalSelfAttention fp32 baseline.
// B=4, T=2048, C=1024, NH=16, HS=64.
// Pipeline: 3x GEMM (q,k,v proj) -> flash attention (causal, online softmax)
//           -> 1x GEMM (output proj).
// Workspace: q,k,v,y each B*T*C fp32 = 32 MiB -> 128 MiB total.

namespace {
constexpr int Bn = 4;
constexpr int Tn = 2048;
constexpr int Cn = 1024;
constexpr int NHn = 16;
constexpr int HSn = 64;

// ---------------- GEMM: C[M,N] = A[M,K] @ B[K,N], fp32 ----------------
// 64x64 tile, BK=16, 256 threads, 4x4 microtile, outer-product inner loop.
// As stored transposed [k][m] so fragment reads are contiguous float4.
// Rows padded to 68 floats: 16B-aligned row starts + spread write banks.
__global__ __launch_bounds__(256) void gemm_ff(
    const float* __restrict__ A, const float* __restrict__ Bw,
    float* __restrict__ Cm, int M, int N, int K) {
  __shared__ float As[16][68];  // [k][m]
  __shared__ float Bs[16][68];  // [k][n]
  const int tid = threadIdx.x;
  const int tx = tid & 15, ty = tid >> 4;
  const int bm = blockIdx.x, bn = blockIdx.y;
  const int arow = tid >> 2, acol = (tid & 3) * 4;   // A: 64 rows x 16 k
  const int brow = tid >> 4, bcol = (tid & 15) * 4;  // B: 16 k x 64 cols
  const float* Ap = A + (size_t)(bm * 64 + arow) * K + acol;
  const float* Bp = Bw + (size_t)brow * N + bn * 64 + bcol;
  float acc[4][4] = {};
  for (int k0 = 0; k0 < K; k0 += 16) {
    const float4 av = *(const float4*)(Ap + k0);
    const float4 bv = *(const float4*)(Bp + (size_t)k0 * N);
    As[acol + 0][arow] = av.x;
    As[acol + 1][arow] = av.y;
    As[acol + 2][arow] = av.z;
    As[acol + 3][arow] = av.w;
    *(float4*)&Bs[brow][bcol] = bv;
    __syncthreads();
#pragma unroll
    for (int kk = 0; kk < 16; ++kk) {
      const float4 a = *(const float4*)&As[kk][ty * 4];
      const float4 b = *(const float4*)&Bs[kk][tx * 4];
      const float ar[4] = {a.x, a.y, a.z, a.w};
      const float br[4] = {b.x, b.y, b.z, b.w};
#pragma unroll
      for (int i = 0; i < 4; ++i)
#pragma unroll
        for (int j = 0; j < 4; ++j) acc[i][j] = fmaf(ar[i], br[j], acc[i][j]);
    }
    __syncthreads();
  }
  float* Cp = Cm + (size_t)(bm * 64 + ty * 4) * N + bn * 64 + tx * 4;
#pragma unroll
  for (int i = 0; i < 4; ++i) {
    const float4 ov = {acc[i][0], acc[i][1], acc[i][2], acc[i][3]};
    *(float4*)(Cp + (size_t)i * N) = ov;
  }
}

// ---------------- Flash attention (causal), fp32 ----------------
// Grid: (T/64, B*NH). Block 256 = 16x16 threads, each owns a 4x4 patch.
// Q tile 64 rows held in LDS (transposed [d][r]); iterate K/V tiles of 64
// up to the causal limit (kt <= qt). Online softmax with per-row running
// max/sum kept redundantly in all 16 lanes of a row-group (lanes tx=0..15
// of each ty — consecutive lanes within one wave, so __shfl_xor width 16
// does the row reduction).
__global__ __launch_bounds__(256) void attn_fwd(
    const float* __restrict__ qg, const float* __restrict__ kg,
    const float* __restrict__ vg, float* __restrict__ yg) {
  __shared__ float Qt[64][68];  // [d][r]
  __shared__ float Kt[64][68];  // [d][c]
  __shared__ float Vs[64][68];  // [k][c] row-major
  __shared__ float Ps[64][65];  // [r][k]
  const int tid = threadIdx.x;
  const int tx = tid & 15, ty = tid >> 4;
  const int qt = blockIdx.x;
  const int bh = blockIdx.y;
  const int b = bh >> 4, h = bh & 15;
  const int q0 = qt * 64;
  const int lr = tid >> 2;        // loader row 0..63
  const int ld = (tid & 3) * 16;  // loader d start
  {
    const float* src = qg + ((size_t)(b * Tn + q0 + lr)) * Cn + h * HSn + ld;
#pragma unroll
    for (int u = 0; u < 4; ++u) {
      const float4 t4 = *(const float4*)(src + u * 4);
      Qt[ld + u * 4 + 0][lr] = t4.x;
      Qt[ld + u * 4 + 1][lr] = t4.y;
      Qt[ld + u * 4 + 2][lr] = t4.z;
      Qt[ld + u * 4 + 3][lr] = t4.w;
    }
  }
  float m_i[4], l_i[4], o[4][4];
#pragma unroll
  for (int i = 0; i < 4; ++i) {
    m_i[i] = -1e30f;
    l_i[i] = 0.f;
#pragma unroll
    for (int j = 0; j < 4; ++j) o[i][j] = 0.f;
  }
  for (int kt = 0; kt <= qt; ++kt) {
    const int k0 = kt * 64;
    __syncthreads();  // prev PV done (Vs/Ps free); Qt ready on first iter
    {
      const float* srck =
          kg + ((size_t)(b * Tn + k0 + lr)) * Cn + h * HSn + ld;
      const float* srcv =
          vg + ((size_t)(b * Tn + k0 + lr)) * Cn + h * HSn + ld;
#pragma unroll
      for (int u = 0; u < 4; ++u) {
        const float4 t4 = *(const float4*)(srck + u * 4);
        Kt[ld + u * 4 + 0][lr] = t4.x;
        Kt[ld + u * 4 + 1][lr] = t4.y;
        Kt[ld + u * 4 + 2][lr] = t4.z;
        Kt[ld + u * 4 + 3][lr] = t4.w;
        *(float4*)&Vs[lr][ld + u * 4] = *(const float4*)(srcv + u * 4);
      }
    }
    __syncthreads();
    // S = (Q K^T) for this tile
    float s[4][4] = {};
#pragma unroll 16
    for (int d = 0; d < 64; ++d) {
      const float4 a = *(const float4*)&Qt[d][ty * 4];
      const float4 bb = *(const float4*)&Kt[d][tx * 4];
      const float ar[4] = {a.x, a.y, a.z, a.w};
      const float br[4] = {bb.x, bb.y, bb.z, bb.w};
#pragma unroll
      for (int i = 0; i < 4; ++i)
#pragma unroll
        for (int j = 0; j < 4; ++j) s[i][j] = fmaf(ar[i], br[j], s[i][j]);
    }
    const bool diag = (kt == qt);
#pragma unroll
    for (int i = 0; i < 4; ++i) {
      const int qrow = q0 + ty * 4 + i;
      float sv[4];
#pragma unroll
      for (int j = 0; j < 4; ++j) {
        float xv = s[i][j] * 0.125f;  // 1/sqrt(64)
        if (diag && (k0 + tx * 4 + j > qrow)) xv = -1e30f;
        sv[j] = xv;
      }
      float rm = fmaxf(fmaxf(sv[0], sv[1]), fmaxf(sv[2], sv[3]));
#pragma unroll
      for (int off = 1; off < 16; off <<= 1)
        rm = fmaxf(rm, __shfl_xor(rm, off, 16));
      const float mnew = fmaxf(m_i[i], rm);
      const float alpha = __expf(m_i[i] - mnew);
      float p[4];
      float rs = 0.f;
#pragma unroll
      for (int j = 0; j < 4; ++j) {
        p[j] = __expf(sv[j] - mnew);
        rs += p[j];
      }
#pragma unroll
      for (int off = 1; off < 16; off <<= 1) rs += __shfl_xor(rs, off, 16);
      l_i[i] = l_i[i] * alpha + rs;
      m_i[i] = mnew;
#pragma unroll
      for (int j = 0; j < 4; ++j) {
        o[i][j] *= alpha;
        Ps[ty * 4 + i][tx * 4 + j] = p[j];
      }
    }
    __syncthreads();
    // O += P @ V
#pragma unroll 8
    for (int kk = 0; kk < 64; ++kk) {
      const float4 vv = *(const float4*)&Vs[kk][tx * 4];
      const float vr[4] = {vv.x, vv.y, vv.z, vv.w};
#pragma unroll
      for (int i = 0; i < 4; ++i) {
        const float p = Ps[ty * 4 + i][kk];  // broadcast within row-group
#pragma unroll
        for (int j = 0; j < 4; ++j) o[i][j] = fmaf(p, vr[j], o[i][j]);
      }
    }
  }
#pragma unroll
  for (int i = 0; i < 4; ++i) {
    const float inv = 1.0f / l_i[i];
    const float4 ov = {o[i][0] * inv, o[i][1] * inv, o[i][2] * inv,
                       o[i][3] * inv};
    *(float4*)(yg + ((size_t)(b * Tn + q0 + ty * 4 + i)) * Cn + h * HSn +
               tx * 4) = ov;
  }
}

}  // namespace

extern "C" void kernel_launch(void* const* d_in, const int* in_sizes, int n_in,
                              void* d_out, int out_size, void* d_ws,
                              size_t ws_size, hipStream_t stream) {
  const float* x = (const float*)d_in[0];
  const float* Wk = (const float*)d_in[1];
  const float* Wq = (const float*)d_in[2];
  const float* Wv = (const float*)d_in[3];
  const float* Wp = (const float*)d_in[4];
  float* out = (float*)d_out;
  float* ws = (float*)d_ws;

  const size_t NEL = (size_t)Bn * Tn * Cn;  // 8388608
  float* qb = ws;
  float* kb = ws + NEL;
  float* vb = ws + 2 * NEL;
  float* yb = ws + 3 * NEL;  // needs 128 MiB of workspace total

  const int M = Bn * Tn, N = Cn, K = Cn;
  const dim3 gg(M / 64, N / 64);  // (128,16)
  const dim3 gb(256);
  gemm_ff<<<gg, gb, 0, stream>>>(x, Wq, qb, M, N, K);
  gemm_ff<<<gg, gb, 0, stream>>>(x, Wk, kb, M, N, K);
  gemm_ff<<<gg, gb, 0, stream>>>(x, Wv, vb, M, N, K);
  attn_fwd<<<dim3(Tn / 64, Bn * NHn), 256, 0, stream>>>(qb, kb, vb, yb);
  gemm_ff<<<gg, gb, 0, stream>>>(yb, Wp, out, M, N, K);
}

// Round 2
// 342.669 us; speedup vs baseline: 5.7616x; 5.7616x over previous
//
#include <hip/hip_runtime.h>
#include <cstddef>
#include <cstdint>

// CausalSelfAttention, bf16-MFMA pipeline.
// B=4, T=2048, C=1024, NH=16, HS=64.
//   cvtx:    x fp32 -> bf16
//   wtrans:  W fp32 [K][N] -> W^T bf16 [N][K]  (x4 weights)
//   gemm_bt: C = A_bf16 . B (B given transposed), m97 structure
//            OUT_MODE 0: bf16 [M][N] (q,k)   1: V^T head-major [b][h][d][t]
//            2: fp32 [M][N] (final out)
//   attn_mfma: flash attention, 64x64 tiles, MFMA QK^T + PV, fp32 softmax.

namespace {

typedef unsigned short u16;
typedef unsigned int u32;
typedef __attribute__((ext_vector_type(8))) short s8v;   // 8 bf16 (4 VGPR)
typedef __attribute__((ext_vector_type(4))) short s4v;
typedef __attribute__((ext_vector_type(4))) float f4v;

constexpr int Bn = 4, Tn = 2048, Cn = 1024, Hn = 16;
constexpr int Mn = Bn * Tn;  // 8192

__device__ __forceinline__ u16 f2bf(float f) {  // RNE fp32->bf16
  u32 u = __float_as_uint(f);
  u32 r = u + 0x7fffu + ((u >> 16) & 1u);
  return (u16)(r >> 16);
}

__device__ __forceinline__ f4v mfma16(s8v a, s8v b, f4v c) {
  return __builtin_amdgcn_mfma_f32_16x16x32_bf16(a, b, c, 0, 0, 0);
}

typedef __attribute__((address_space(1))) const u32 gas_u32;
typedef __attribute__((address_space(3))) u32 las_u32;
__device__ __forceinline__ void gl_lds16(const void* g, void* l) {
  __builtin_amdgcn_global_load_lds((gas_u32*)g, (las_u32*)l, 16, 0, 0);
}

// ---------------- x -> bf16 ----------------
__global__ __launch_bounds__(256) void cvtx(const float* __restrict__ in,
                                            u16* __restrict__ out) {
  const size_t i = ((size_t)blockIdx.x * 256 + threadIdx.x) * 8;
  const float4 a = *(const float4*)(in + i);
  const float4 b = *(const float4*)(in + i + 4);
  alignas(16) u16 t[8] = {f2bf(a.x), f2bf(a.y), f2bf(a.z), f2bf(a.w),
                          f2bf(b.x), f2bf(b.y), f2bf(b.z), f2bf(b.w)};
  *(s8v*)(out + i) = *(const s8v*)t;
}

// ---------------- W [K][N] fp32 -> W^T [N][K] bf16 ----------------
__global__ __launch_bounds__(256) void wtrans(
    const float* __restrict__ w0, const float* __restrict__ w1,
    const float* __restrict__ w2, const float* __restrict__ w3,
    u16* __restrict__ o0, u16* __restrict__ o1, u16* __restrict__ o2,
    u16* __restrict__ o3) {
  const float* W;
  u16* O;
  switch (blockIdx.z) {
    case 0: W = w0; O = o0; break;
    case 1: W = w1; O = o1; break;
    case 2: W = w2; O = o2; break;
    default: W = w3; O = o3; break;
  }
  __shared__ float Tsh[64][65];
  const int tid = threadIdx.x;
  const int n0 = blockIdx.x * 64, k0 = blockIdx.y * 64;
  {
    const int rk = tid >> 2, c0 = (tid & 3) * 16;
#pragma unroll
    for (int u = 0; u < 4; ++u) {
      const float4 v = *(const float4*)&W[(size_t)(k0 + rk) * Cn + n0 + c0 + u * 4];
      Tsh[rk][c0 + u * 4 + 0] = v.x;
      Tsh[rk][c0 + u * 4 + 1] = v.y;
      Tsh[rk][c0 + u * 4 + 2] = v.z;
      Tsh[rk][c0 + u * 4 + 3] = v.w;
    }
  }
  __syncthreads();
  {
    const int rn = tid >> 2, ck0 = (tid & 3) * 16;
    alignas(16) u16 t[16];
#pragma unroll
    for (int u = 0; u < 16; ++u) t[u] = f2bf(Tsh[ck0 + u][rn]);
    *(s8v*)&O[(size_t)(n0 + rn) * Cn + k0 + ck0] = *(const s8v*)&t[0];
    *(s8v*)&O[(size_t)(n0 + rn) * Cn + k0 + ck0 + 8] = *(const s8v*)&t[8];
  }
}

// ---------------- GEMM (m97 structure) ----------------
// C[M,N] = A[M,K] . B[K,N], with Bt = B^T [N][K] supplied.
// 128x128 tile, BK=32, 256 threads = 4 waves (2x2 of 64x64).
template <int OUT_MODE>
__global__ __launch_bounds__(256) void gemm_bt(const u16* __restrict__ A,
                                               const u16* __restrict__ Bt,
                                               void* __restrict__ Cout, int M,
                                               int N, int K) {
  __shared__ __align__(16) u16 As[4096];  // [128 rows][32 k] linear
  __shared__ __align__(16) u16 Bs[4096];  // [128 cols][32 k] linear
  const int tid = threadIdx.x;
  const int l = tid & 63, w = tid >> 6;
  const int lr = l & 15, lh = l >> 4;
  const int bm = blockIdx.x, bn = blockIdx.y;
  const int lrow = tid >> 2;            // loader row 0..63 (+64 second issue)
  const int lkcol = (tid & 3) * 8;      // loader k offset
  const u16* Ag = A + (size_t)(bm * 128 + lrow) * K + lkcol;
  const u16* Bg = Bt + (size_t)(bn * 128 + lrow) * K + lkcol;
  const int wm = (w >> 1) * 64, wn = (w & 1) * 64;
  f4v acc[4][4] = {};
  for (int k0 = 0; k0 < K; k0 += 32) {
    __syncthreads();  // previous tile's reads done
    gl_lds16(Ag + k0, &As[(size_t)tid * 8]);
    gl_lds16(Ag + (size_t)64 * K + k0, &As[2048 + (size_t)tid * 8]);
    gl_lds16(Bg + k0, &Bs[(size_t)tid * 8]);
    gl_lds16(Bg + (size_t)64 * K + k0, &Bs[2048 + (size_t)tid * 8]);
    __syncthreads();  // vmcnt(0) drained by barrier
    s8v af[4], bfr[4];
#pragma unroll
    for (int i = 0; i < 4; ++i)
      af[i] = *(const s8v*)&As[(wm + i * 16 + lr) * 32 + lh * 8];
#pragma unroll
    for (int j = 0; j < 4; ++j)
      bfr[j] = *(const s8v*)&Bs[(wn + j * 16 + lr) * 32 + lh * 8];
#pragma unroll
    for (int i = 0; i < 4; ++i)
#pragma unroll
      for (int j = 0; j < 4; ++j)
        acc[i][j] = mfma16(af[i], bfr[j], acc[i][j]);
  }
  // Epilogue. D layout: col = lane&15, row = (lane>>4)*4 + reg  [m89]
  if (OUT_MODE == 2) {
    float* Cf = (float*)Cout;
#pragma unroll
    for (int i = 0; i < 4; ++i) {
      const int row = bm * 128 + wm + i * 16 + lh * 4;
#pragma unroll
      for (int j = 0; j < 4; ++j) {
        const int col = bn * 128 + wn + j * 16 + lr;
#pragma unroll
        for (int r = 0; r < 4; ++r)
          Cf[(size_t)(row + r) * N + col] = acc[i][j][r];
      }
    }
  } else if (OUT_MODE == 0) {
    u16* Cb = (u16*)Cout;
#pragma unroll
    for (int i = 0; i < 4; ++i) {
      const int row = bm * 128 + wm + i * 16 + lh * 4;
#pragma unroll
      for (int j = 0; j < 4; ++j) {
        const int col = bn * 128 + wn + j * 16 + lr;
#pragma unroll
        for (int r = 0; r < 4; ++r)
          Cb[(size_t)(row + r) * N + col] = f2bf(acc[i][j][r]);
      }
    }
  } else {
    // V^T head-major: Vt[((b*16+h)*64+d)][t]; 4 regs = 4 consecutive t
    u16* Vt = (u16*)Cout;
#pragma unroll
    for (int i = 0; i < 4; ++i) {
      const int row0 = bm * 128 + wm + i * 16 + lh * 4;  // t (global M row)
      const int bq = row0 >> 11, t0 = row0 & 2047;
#pragma unroll
      for (int j = 0; j < 4; ++j) {
        const int col = bn * 128 + wn + j * 16 + lr;  // h*64+d
        const int hh = col >> 6, dd = col & 63;
        alignas(8) u16 t4[4];
#pragma unroll
        for (int r = 0; r < 4; ++r) t4[r] = f2bf(acc[i][j][r]);
        *(s4v*)&Vt[((size_t)((bq * 16 + hh) * 64 + dd)) * Tn + t0] =
            *(const s4v*)t4;
      }
    }
  }
}

// ---------------- Flash attention, bf16 MFMA ----------------
// Block: (qt, b*16+h), 256 threads = 4 waves; wave w owns q-rows w*16..+16.
// LDS rows are 64 bf16 = 128 B -> XOR swizzle elem: d ^= (row&7)<<3.
__global__ __launch_bounds__(256) void attn_mfma(const u16* __restrict__ qg,
                                                 const u16* __restrict__ kg,
                                                 const u16* __restrict__ vtg,
                                                 u16* __restrict__ yg) {
  __shared__ __align__(16) u16 Qs[4096], Ks[4096], Vs[4096], Ps[4096];
  const int tid = threadIdx.x;
  const int l = tid & 63, w = tid >> 6;
  const int lr = l & 15, lh = l >> 4;
  const int qt = blockIdx.x, bh = blockIdx.y;
  const int b = bh >> 4, h = bh & 15;
  const int q0 = qt * 64;
  {
    const int d0 = (tid & 7) * 8;
#pragma unroll
    for (int it = 0; it < 2; ++it) {
      const int row = it * 32 + (tid >> 3);
      const s8v v = *(const s8v*)&qg[(size_t)(b * Tn + q0 + row) * Cn + h * 64 + d0];
      *(s8v*)&Qs[row * 64 + (d0 ^ ((row & 7) << 3))] = v;
    }
  }
  float m_i[4] = {-1e30f, -1e30f, -1e30f, -1e30f};
  float l_i[4] = {0.f, 0.f, 0.f, 0.f};
  f4v o[4] = {};
  for (int kt = 0; kt <= qt; ++kt) {
    const int k0 = kt * 64;
    __syncthreads();  // prev tile's K/V reads done (also covers Qs first iter)
    {
      const int d0 = (tid & 7) * 8;
#pragma unroll
      for (int it = 0; it < 2; ++it) {
        const int row = it * 32 + (tid >> 3);
        const s8v kv = *(const s8v*)&kg[(size_t)(b * Tn + k0 + row) * Cn + h * 64 + d0];
        *(s8v*)&Ks[row * 64 + (d0 ^ ((row & 7) << 3))] = kv;
        const s8v vv = *(const s8v*)&vtg[((size_t)(bh * 64 + row)) * Tn + k0 + d0];
        *(s8v*)&Vs[row * 64 + (d0 ^ ((row & 7) << 3))] = vv;
      }
    }
    __syncthreads();
    // S = Q K^T  (A = Q rows, B = K rows as B^T)
    f4v s[4] = {};
    {
      s8v aq[2];
      const int row = w * 16 + lr;
#pragma unroll
      for (int kd = 0; kd < 2; ++kd)
        aq[kd] = *(const s8v*)&Qs[row * 64 + ((kd * 32 + lh * 8) ^ ((row & 7) << 3))];
#pragma unroll
      for (int n = 0; n < 4; ++n) {
        const int rk = n * 16 + lr;
#pragma unroll
        for (int kd = 0; kd < 2; ++kd) {
          const s8v bk = *(const s8v*)&Ks[rk * 64 + ((kd * 32 + lh * 8) ^ ((rk & 7) << 3))];
          s[n] = mfma16(aq[kd], bk, s[n]);
        }
      }
    }
    const bool diag = (kt == qt);
#pragma unroll
    for (int r = 0; r < 4; ++r) {
      const int qrow_l = w * 16 + lh * 4 + r;  // local q row (q0==k0 on diag)
      float sv[4];
#pragma unroll
      for (int n = 0; n < 4; ++n) {
        float x = s[n][r] * 0.125f;  // 1/sqrt(64)
        if (diag && (n * 16 + lr > qrow_l)) x = -1e30f;
        sv[n] = x;
      }
      float rm = fmaxf(fmaxf(sv[0], sv[1]), fmaxf(sv[2], sv[3]));
#pragma unroll
      for (int off = 1; off < 16; off <<= 1)
        rm = fmaxf(rm, __shfl_xor(rm, off, 16));
      const float mnew = fmaxf(m_i[r], rm);
      const float alpha = __expf(m_i[r] - mnew);
      float p[4], rs = 0.f;
#pragma unroll
      for (int n = 0; n < 4; ++n) {
        p[n] = __expf(sv[n] - mnew);
        rs += p[n];
      }
#pragma unroll
      for (int off = 1; off < 16; off <<= 1) rs += __shfl_xor(rs, off, 16);
      l_i[r] = l_i[r] * alpha + rs;
      m_i[r] = mnew;
#pragma unroll
      for (int n = 0; n < 4; ++n) o[n][r] *= alpha;
#pragma unroll
      for (int n = 0; n < 4; ++n)
        Ps[qrow_l * 64 + ((n * 16 + lr) ^ ((qrow_l & 7) << 3))] = f2bf(p[n]);
    }
    // O += P V   (A = P rows, B = V^T rows [d][kc])
    {
      s8v ap[2];
      const int row = w * 16 + lr;
#pragma unroll
      for (int kh = 0; kh < 2; ++kh)
        ap[kh] = *(const s8v*)&Ps[row * 64 + ((kh * 32 + lh * 8) ^ ((row & 7) << 3))];
#pragma unroll
      for (int n = 0; n < 4; ++n) {
        const int rv = n * 16 + lr;
#pragma unroll
        for (int kh = 0; kh < 2; ++kh) {
          const s8v bv = *(const s8v*)&Vs[rv * 64 + ((kh * 32 + lh * 8) ^ ((rv & 7) << 3))];
          o[n] = mfma16(ap[kh], bv, o[n]);
        }
      }
    }
  }
#pragma unroll
  for (int r = 0; r < 4; ++r) {
    const float inv = 1.0f / l_i[r];
    const int row = q0 + w * 16 + lh * 4 + r;
#pragma unroll
    for (int n = 0; n < 4; ++n)
      yg[(size_t)(b * Tn + row) * Cn + h * 64 + n * 16 + lr] =
          f2bf(o[n][r] * inv);
  }
}

}  // namespace

extern "C" void kernel_launch(void* const* d_in, const int* in_sizes, int n_in,
                              void* d_out, int out_size, void* d_ws,
                              size_t ws_size, hipStream_t stream) {
  (void)in_sizes; (void)n_in; (void)out_size; (void)ws_size;
  const float* x = (const float*)d_in[0];
  const float* Wk = (const float*)d_in[1];
  const float* Wq = (const float*)d_in[2];
  const float* Wv = (const float*)d_in[3];
  const float* Wp = (const float*)d_in[4];
  float* out = (float*)d_out;
  char* ws = (char*)d_ws;

  // byte offsets in workspace (total 92,274,688 B)
  u16* xb = (u16*)(ws);                   // 16.8 MB
  u16* wqt = (u16*)(ws + 16777216);       // 2 MB each
  u16* wkt = (u16*)(ws + 18874368);
  u16* wvt = (u16*)(ws + 20971520);
  u16* wpt = (u16*)(ws + 23068672);
  u16* qb = (u16*)(ws + 25165824);        // 16.8 MB each
  u16* kb = (u16*)(ws + 41943040);
  u16* vt = (u16*)(ws + 58720256);        // head-major V^T [b][h][d][t]
  u16* yb = (u16*)(ws + 75497472);

  cvtx<<<dim3(4096), dim3(256), 0, stream>>>(x, xb);
  wtrans<<<dim3(16, 16, 4), dim3(256), 0, stream>>>(Wq, Wk, Wv, Wp, wqt, wkt,
                                                    wvt, wpt);
  gemm_bt<0><<<dim3(64, 8), dim3(256), 0, stream>>>(xb, wqt, qb, Mn, Cn, Cn);
  gemm_bt<0><<<dim3(64, 8), dim3(256), 0, stream>>>(xb, wkt, kb, Mn, Cn, Cn);
  gemm_bt<1><<<dim3(64, 8), dim3(256), 0, stream>>>(xb, wvt, vt, Mn, Cn, Cn);
  attn_mfma<<<dim3(32, 64), dim3(256), 0, stream>>>(qb, kb, vt, yb);
  gemm_bt<2><<<dim3(64, 8), dim3(256), 0, stream>>>(yb, wpt, out, Mn, Cn, Cn);
}

// Round 3
// 268.706 us; speedup vs baseline: 7.3476x; 1.2753x over previous
//
#include <hip/hip_runtime.h>
#include <cstddef>
#include <cstdint>

// CausalSelfAttention, bf16-MFMA pipeline, round 3.
// B=4, T=2048, C=1024, NH=16, HS=64.
//   cvtx:    x fp32 -> bf16
//   wtrans:  W fp32 [K][N] -> W^T bf16 [N][K]  (x4 weights)
//   gemm_bt: C = A_bf16 . B^T-supplied, m97 structure, XCD-swizzled 1D grid
//   attn_pair: flash attention; each block handles paired q-tiles (xp, 31-xp)
//              for uniform work; shared K/V staging; reg-prefetch (T14);
//              setprio around MFMA (T5); XCD swizzle (T1).

namespace {

typedef unsigned short u16;
typedef unsigned int u32;
typedef __attribute__((ext_vector_type(8))) short s8v;   // 8 bf16 (4 VGPR)
typedef __attribute__((ext_vector_type(4))) short s4v;
typedef __attribute__((ext_vector_type(4))) float f4v;

constexpr int Bn = 4, Tn = 2048, Cn = 1024;
constexpr int Mn = Bn * Tn;  // 8192
constexpr int NTq = Tn / 64; // 32 k/q tiles

__device__ __forceinline__ u16 f2bf(float f) {  // RNE fp32->bf16
  u32 u = __float_as_uint(f);
  u32 r = u + 0x7fffu + ((u >> 16) & 1u);
  return (u16)(r >> 16);
}

__device__ __forceinline__ f4v mfma16(s8v a, s8v b, f4v c) {
  return __builtin_amdgcn_mfma_f32_16x16x32_bf16(a, b, c, 0, 0, 0);
}

typedef __attribute__((address_space(1))) const u32 gas_u32;
typedef __attribute__((address_space(3))) u32 las_u32;
__device__ __forceinline__ void gl_lds16(const void* g, void* l) {
  __builtin_amdgcn_global_load_lds((gas_u32*)g, (las_u32*)l, 16, 0, 0);
}

// ---------------- x -> bf16 ----------------
__global__ __launch_bounds__(256) void cvtx(const float* __restrict__ in,
                                            u16* __restrict__ out) {
  const size_t i = ((size_t)blockIdx.x * 256 + threadIdx.x) * 8;
  const float4 a = *(const float4*)(in + i);
  const float4 b = *(const float4*)(in + i + 4);
  alignas(16) u16 t[8] = {f2bf(a.x), f2bf(a.y), f2bf(a.z), f2bf(a.w),
                          f2bf(b.x), f2bf(b.y), f2bf(b.z), f2bf(b.w)};
  *(s8v*)(out + i) = *(const s8v*)t;
}

// ---------------- W [K][N] fp32 -> W^T [N][K] bf16 ----------------
__global__ __launch_bounds__(256) void wtrans(
    const float* __restrict__ w0, const float* __restrict__ w1,
    const float* __restrict__ w2, const float* __restrict__ w3,
    u16* __restrict__ o0, u16* __restrict__ o1, u16* __restrict__ o2,
    u16* __restrict__ o3) {
  const float* W;
  u16* O;
  switch (blockIdx.z) {
    case 0: W = w0; O = o0; break;
    case 1: W = w1; O = o1; break;
    case 2: W = w2; O = o2; break;
    default: W = w3; O = o3; break;
  }
  __shared__ float Tsh[64][65];
  const int tid = threadIdx.x;
  const int n0 = blockIdx.x * 64, k0 = blockIdx.y * 64;
  {
    const int rk = tid >> 2, c0 = (tid & 3) * 16;
#pragma unroll
    for (int u = 0; u < 4; ++u) {
      const float4 v = *(const float4*)&W[(size_t)(k0 + rk) * Cn + n0 + c0 + u * 4];
      Tsh[rk][c0 + u * 4 + 0] = v.x;
      Tsh[rk][c0 + u * 4 + 1] = v.y;
      Tsh[rk][c0 + u * 4 + 2] = v.z;
      Tsh[rk][c0 + u * 4 + 3] = v.w;
    }
  }
  __syncthreads();
  {
    const int rn = tid >> 2, ck0 = (tid & 3) * 16;
    alignas(16) u16 t[16];
#pragma unroll
    for (int u = 0; u < 16; ++u) t[u] = f2bf(Tsh[ck0 + u][rn]);
    *(s8v*)&O[(size_t)(n0 + rn) * Cn + k0 + ck0] = *(const s8v*)&t[0];
    *(s8v*)&O[(size_t)(n0 + rn) * Cn + k0 + ck0 + 8] = *(const s8v*)&t[8];
  }
}

// ---------------- GEMM (m97 structure, XCD-swizzled) ----------------
// C[M,N] = A[M,K] . B[K,N], Bt = B^T [N][K] supplied. Grid: 1D, 512 blocks
// (M/128=64 x N/128=8). XCD bijective swizzle (512 % 8 == 0).
template <int OUT_MODE>
__global__ __launch_bounds__(256) void gemm_bt(const u16* __restrict__ A,
                                               const u16* __restrict__ Bt,
                                               void* __restrict__ Cout, int M,
                                               int N, int K) {
  __shared__ __align__(16) u16 As[4096];  // [128 rows][32 k] linear
  __shared__ __align__(16) u16 Bs[4096];  // [128 cols][32 k] linear
  const int tid = threadIdx.x;
  const int l = tid & 63, w = tid >> 6;
  const int lr = l & 15, lh = l >> 4;
  const int bid = blockIdx.x;                 // 0..511
  const int wg = (bid & 7) * 64 + (bid >> 3); // XCD chunking
  const int bm = wg & 63, bn = wg >> 6;
  const int lrow = tid >> 2;
  const int lkcol = (tid & 3) * 8;
  const u16* Ag = A + (size_t)(bm * 128 + lrow) * K + lkcol;
  const u16* Bg = Bt + (size_t)(bn * 128 + lrow) * K + lkcol;
  const int wm = (w >> 1) * 64, wn = (w & 1) * 64;
  f4v acc[4][4] = {};
  for (int k0 = 0; k0 < K; k0 += 32) {
    __syncthreads();
    gl_lds16(Ag + k0, &As[(size_t)tid * 8]);
    gl_lds16(Ag + (size_t)64 * K + k0, &As[2048 + (size_t)tid * 8]);
    gl_lds16(Bg + k0, &Bs[(size_t)tid * 8]);
    gl_lds16(Bg + (size_t)64 * K + k0, &Bs[2048 + (size_t)tid * 8]);
    __syncthreads();
    s8v af[4], bfr[4];
#pragma unroll
    for (int i = 0; i < 4; ++i)
      af[i] = *(const s8v*)&As[(wm + i * 16 + lr) * 32 + lh * 8];
#pragma unroll
    for (int j = 0; j < 4; ++j)
      bfr[j] = *(const s8v*)&Bs[(wn + j * 16 + lr) * 32 + lh * 8];
    __builtin_amdgcn_s_setprio(1);
#pragma unroll
    for (int i = 0; i < 4; ++i)
#pragma unroll
      for (int j = 0; j < 4; ++j)
        acc[i][j] = mfma16(af[i], bfr[j], acc[i][j]);
    __builtin_amdgcn_s_setprio(0);
  }
  // D layout: col = lane&15, row = (lane>>4)*4 + reg  [m89]
  if (OUT_MODE == 2) {
    float* Cf = (float*)Cout;
#pragma unroll
    for (int i = 0; i < 4; ++i) {
      const int row = bm * 128 + wm + i * 16 + lh * 4;
#pragma unroll
      for (int j = 0; j < 4; ++j) {
        const int col = bn * 128 + wn + j * 16 + lr;
#pragma unroll
        for (int r = 0; r < 4; ++r)
          Cf[(size_t)(row + r) * N + col] = acc[i][j][r];
      }
    }
  } else if (OUT_MODE == 0) {
    u16* Cb = (u16*)Cout;
#pragma unroll
    for (int i = 0; i < 4; ++i) {
      const int row = bm * 128 + wm + i * 16 + lh * 4;
#pragma unroll
      for (int j = 0; j < 4; ++j) {
        const int col = bn * 128 + wn + j * 16 + lr;
#pragma unroll
        for (int r = 0; r < 4; ++r)
          Cb[(size_t)(row + r) * N + col] = f2bf(acc[i][j][r]);
      }
    }
  } else {
    // V^T head-major: Vt[((b*16+h)*64+d)][t]; 4 regs = 4 consecutive t
    u16* Vt = (u16*)Cout;
#pragma unroll
    for (int i = 0; i < 4; ++i) {
      const int row0 = bm * 128 + wm + i * 16 + lh * 4;
      const int bq = row0 >> 11, t0 = row0 & 2047;
#pragma unroll
      for (int j = 0; j < 4; ++j) {
        const int col = bn * 128 + wn + j * 16 + lr;
        const int hh = col >> 6, dd = col & 63;
        alignas(8) u16 t4[4];
#pragma unroll
        for (int r = 0; r < 4; ++r) t4[r] = f2bf(acc[i][j][r]);
        *(s4v*)&Vt[((size_t)((bq * 16 + hh) * 64 + dd)) * Tn + t0] =
            *(const s4v*)t4;
      }
    }
  }
}

// ---------------- Flash attention, paired q-tiles ----------------
// One step: QK^T + online softmax + PV for one 64-row q-tile against the
// currently staged 64-row K/V tile. All layouts identical to round-2 kernel.
__device__ __forceinline__ void attn_step(const u16* __restrict__ Qs,
                                          const u16* __restrict__ Ks,
                                          const u16* __restrict__ Vs,
                                          u16* __restrict__ Ps, int w, int lr,
                                          int lh, bool diag, float* m_i,
                                          float* l_i, f4v* o) {
  f4v s[4] = {};
  {
    const int row = w * 16 + lr;
    const int sw = (row & 7) << 3;
    const s8v aq0 = *(const s8v*)&Qs[row * 64 + ((lh * 8) ^ sw)];
    const s8v aq1 = *(const s8v*)&Qs[row * 64 + ((32 + lh * 8) ^ sw)];
    __builtin_amdgcn_s_setprio(1);
#pragma unroll
    for (int n = 0; n < 4; ++n) {
      const int rk = n * 16 + lr;
      const int swk = (rk & 7) << 3;
      const s8v bk0 = *(const s8v*)&Ks[rk * 64 + ((lh * 8) ^ swk)];
      const s8v bk1 = *(const s8v*)&Ks[rk * 64 + ((32 + lh * 8) ^ swk)];
      s[n] = mfma16(aq0, bk0, s[n]);
      s[n] = mfma16(aq1, bk1, s[n]);
    }
    __builtin_amdgcn_s_setprio(0);
  }
#pragma unroll
  for (int r = 0; r < 4; ++r) {
    const int qrow_l = w * 16 + lh * 4 + r;
    float sv[4];
#pragma unroll
    for (int n = 0; n < 4; ++n) {
      float x = s[n][r] * 0.125f;  // 1/sqrt(64)
      if (diag && (n * 16 + lr > qrow_l)) x = -1e30f;
      sv[n] = x;
    }
    float rm = fmaxf(fmaxf(sv[0], sv[1]), fmaxf(sv[2], sv[3]));
#pragma unroll
    for (int off = 1; off < 16; off <<= 1)
      rm = fmaxf(rm, __shfl_xor(rm, off, 16));
    const float mnew = fmaxf(m_i[r], rm);
    const float alpha = __expf(m_i[r] - mnew);
    float p[4], rs = 0.f;
#pragma unroll
    for (int n = 0; n < 4; ++n) {
      p[n] = __expf(sv[n] - mnew);
      rs += p[n];
    }
#pragma unroll
    for (int off = 1; off < 16; off <<= 1) rs += __shfl_xor(rs, off, 16);
    l_i[r] = l_i[r] * alpha + rs;
    m_i[r] = mnew;
#pragma unroll
    for (int n = 0; n < 4; ++n) o[n][r] *= alpha;
    const int swp = (qrow_l & 7) << 3;
#pragma unroll
    for (int n = 0; n < 4; ++n)
      Ps[qrow_l * 64 + ((n * 16 + lr) ^ swp)] = f2bf(p[n]);
  }
  {
    const int row = w * 16 + lr;
    const int sw = (row & 7) << 3;
    const s8v ap0 = *(const s8v*)&Ps[row * 64 + ((lh * 8) ^ sw)];
    const s8v ap1 = *(const s8v*)&Ps[row * 64 + ((32 + lh * 8) ^ sw)];
    __builtin_amdgcn_s_setprio(1);
#pragma unroll
    for (int n = 0; n < 4; ++n) {
      const int rv = n * 16 + lr;
      const int swv = (rv & 7) << 3;
      const s8v bv0 = *(const s8v*)&Vs[rv * 64 + ((lh * 8) ^ swv)];
      const s8v bv1 = *(const s8v*)&Vs[rv * 64 + ((32 + lh * 8) ^ swv)];
      o[n] = mfma16(ap0, bv0, o[n]);
      o[n] = mfma16(ap1, bv1, o[n]);
    }
    __builtin_amdgcn_s_setprio(0);
  }
}

// Block: paired q-tiles (xp, 31-xp) -> uniform 33 tile-steps per block.
// Grid: 1024 blocks (16 pairs x 64 bh), XCD-swizzled. 4 waves, each owns
// 16 q-rows of each tile. K/V staged once per kt, shared by both q-tiles.
__global__ __launch_bounds__(256) void attn_pair(const u16* __restrict__ qg,
                                                 const u16* __restrict__ kg,
                                                 const u16* __restrict__ vtg,
                                                 u16* __restrict__ yg) {
  __shared__ __align__(16) u16 QsL[4096], QsH[4096], Ks[4096], Vs[4096],
      Ps[4096];
  const int tid = threadIdx.x;
  const int l = tid & 63, w = tid >> 6;
  const int lr = l & 15, lh = l >> 4;
  const int bid = blockIdx.x;                   // 0..1023
  const int wg = (bid & 7) * 128 + (bid >> 3);  // XCD chunking (1024%8==0)
  const int bh = wg >> 4, xp = wg & 15;
  const int b = bh >> 4, h = bh & 15;
  const int qtL = xp, qtH = NTq - 1 - xp;  // qtL in [0,15], qtH in [16,31]
  const int q0L = qtL * 64, q0H = qtH * 64;
  const int d0 = (tid & 7) * 8;
  const int lrow = tid >> 3;  // 0..31
  {
#pragma unroll
    for (int it = 0; it < 2; ++it) {
      const int row = it * 32 + lrow;
      const int sw = d0 ^ ((row & 7) << 3);
      *(s8v*)&QsL[row * 64 + sw] =
          *(const s8v*)&qg[(size_t)(b * Tn + q0L + row) * Cn + h * 64 + d0];
      *(s8v*)&QsH[row * 64 + sw] =
          *(const s8v*)&qg[(size_t)(b * Tn + q0H + row) * Cn + h * 64 + d0];
    }
  }
  float mL[4] = {-1e30f, -1e30f, -1e30f, -1e30f}, lL[4] = {0.f, 0.f, 0.f, 0.f};
  float mH[4] = {-1e30f, -1e30f, -1e30f, -1e30f}, lH[4] = {0.f, 0.f, 0.f, 0.f};
  f4v oL[4] = {}, oH[4] = {};
  // reg prefetch (T14): K rows and V^T rows for tile kt
  s8v kr0, kr1, vr0, vr1;
  {
    const int r0 = lrow, r1 = 32 + lrow;
    kr0 = *(const s8v*)&kg[(size_t)(b * Tn + 0 + r0) * Cn + h * 64 + d0];
    kr1 = *(const s8v*)&kg[(size_t)(b * Tn + 0 + r1) * Cn + h * 64 + d0];
    vr0 = *(const s8v*)&vtg[((size_t)(bh * 64 + r0)) * Tn + 0 + d0];
    vr1 = *(const s8v*)&vtg[((size_t)(bh * 64 + r1)) * Tn + 0 + d0];
  }
  for (int kt = 0; kt <= qtH; ++kt) {
    __syncthreads();  // all waves done reading Ks/Vs of kt-1 (covers Qs @kt=0)
    {
      const int r0 = lrow, r1 = 32 + lrow;
      const int sw0 = d0 ^ ((r0 & 7) << 3), sw1 = d0 ^ ((r1 & 7) << 3);
      *(s8v*)&Ks[r0 * 64 + sw0] = kr0;
      *(s8v*)&Ks[r1 * 64 + sw1] = kr1;
      *(s8v*)&Vs[r0 * 64 + sw0] = vr0;
      *(s8v*)&Vs[r1 * 64 + sw1] = vr1;
    }
    __syncthreads();
    if (kt < qtH) {  // issue next tile's loads; latency hides under compute
      const int k0n = (kt + 1) * 64;
      const int r0 = lrow, r1 = 32 + lrow;
      kr0 = *(const s8v*)&kg[(size_t)(b * Tn + k0n + r0) * Cn + h * 64 + d0];
      kr1 = *(const s8v*)&kg[(size_t)(b * Tn + k0n + r1) * Cn + h * 64 + d0];
      vr0 = *(const s8v*)&vtg[((size_t)(bh * 64 + r0)) * Tn + k0n + d0];
      vr1 = *(const s8v*)&vtg[((size_t)(bh * 64 + r1)) * Tn + k0n + d0];
    }
    attn_step(QsH, Ks, Vs, Ps, w, lr, lh, kt == qtH, mH, lH, oH);
    if (kt <= qtL)
      attn_step(QsL, Ks, Vs, Ps, w, lr, lh, kt == qtL, mL, lL, oL);
  }
#pragma unroll
  for (int r = 0; r < 4; ++r) {
    const float invH = 1.0f / lH[r];
    const float invL = 1.0f / lL[r];
    const int rowH = q0H + w * 16 + lh * 4 + r;
    const int rowL = q0L + w * 16 + lh * 4 + r;
#pragma unroll
    for (int n = 0; n < 4; ++n) {
      yg[(size_t)(b * Tn + rowH) * Cn + h * 64 + n * 16 + lr] =
          f2bf(oH[n][r] * invH);
      yg[(size_t)(b * Tn + rowL) * Cn + h * 64 + n * 16 + lr] =
          f2bf(oL[n][r] * invL);
    }
  }
}

}  // namespace

extern "C" void kernel_launch(void* const* d_in, const int* in_sizes, int n_in,
                              void* d_out, int out_size, void* d_ws,
                              size_t ws_size, hipStream_t stream) {
  (void)in_sizes; (void)n_in; (void)out_size; (void)ws_size;
  const float* x = (const float*)d_in[0];
  const float* Wk = (const float*)d_in[1];
  const float* Wq = (const float*)d_in[2];
  const float* Wv = (const float*)d_in[3];
  const float* Wp = (const float*)d_in[4];
  float* out = (float*)d_out;
  char* ws = (char*)d_ws;

  u16* xb = (u16*)(ws);                   // 16.8 MB
  u16* wqt = (u16*)(ws + 16777216);       // 2 MB each
  u16* wkt = (u16*)(ws + 18874368);
  u16* wvt = (u16*)(ws + 20971520);
  u16* wpt = (u16*)(ws + 23068672);
  u16* qb = (u16*)(ws + 25165824);        // 16.8 MB each
  u16* kb = (u16*)(ws + 41943040);
  u16* vt = (u16*)(ws + 58720256);        // head-major V^T [b][h][d][t]
  u16* yb = (u16*)(ws + 75497472);

  cvtx<<<dim3(4096), dim3(256), 0, stream>>>(x, xb);
  wtrans<<<dim3(16, 16, 4), dim3(256), 0, stream>>>(Wq, Wk, Wv, Wp, wqt, wkt,
                                                    wvt, wpt);
  gemm_bt<0><<<dim3(512), dim3(256), 0, stream>>>(xb, wqt, qb, Mn, Cn, Cn);
  gemm_bt<0><<<dim3(512), dim3(256), 0, stream>>>(xb, wkt, kb, Mn, Cn, Cn);
  gemm_bt<1><<<dim3(512), dim3(256), 0, stream>>>(xb, wvt, vt, Mn, Cn, Cn);
  attn_pair<<<dim3(1024), dim3(256), 0, stream>>>(qb, kb, vt, yb);
  gemm_bt<2><<<dim3(512), dim3(256), 0, stream>>>(yb, wpt, out, Mn, Cn, Cn);
}

// Round 4
// 229.737 us; speedup vs baseline: 8.5939x; 1.1696x over previous
//
#include <hip/hip_runtime.h>
#include <cstddef>
#include <cstdint>

// CausalSelfAttention, bf16-MFMA pipeline, round 4.
// B=4, T=2048, C=1024, NH=16, HS=64.
//   cvtx:      x fp32 -> bf16
//   wtrans:    W fp32 [K][N] -> W^T bf16 [N][K]  (x4 weights)
//   gemm_qkv:  fused q/k/v projection (3x GEMM, one dispatch)
//   gemm_bt<2>: output projection
//   attn_big:  flash attention; 128-row paired q-tiles (xp, 15-xp), KVB=128,
//              8 waves, Q in registers, defer-max (T13), reg-prefetch (T14),
//              setprio (T5), XCD swizzle (T1), chunk-XOR LDS swizzle (T2).

namespace {

typedef unsigned short u16;
typedef unsigned int u32;
typedef __attribute__((ext_vector_type(8))) short s8v;   // 8 bf16 (4 VGPR)
typedef __attribute__((ext_vector_type(4))) short s4v;
typedef __attribute__((ext_vector_type(4))) float f4v;

constexpr int Bn = 4, Tn = 2048, Cn = 1024;
constexpr int Mn = Bn * Tn;   // 8192
constexpr int KVB = 128;      // k-tile rows
constexpr int NT128 = Tn / 128;  // 16 tiles of 128

__device__ __forceinline__ u16 f2bf(float f) {  // RNE fp32->bf16
  u32 u = __float_as_uint(f);
  u32 r = u + 0x7fffu + ((u >> 16) & 1u);
  return (u16)(r >> 16);
}

__device__ __forceinline__ f4v mfma16(s8v a, s8v b, f4v c) {
  return __builtin_amdgcn_mfma_f32_16x16x32_bf16(a, b, c, 0, 0, 0);
}

typedef __attribute__((address_space(1))) const u32 gas_u32;
typedef __attribute__((address_space(3))) u32 las_u32;
__device__ __forceinline__ void gl_lds16(const void* g, void* l) {
  __builtin_amdgcn_global_load_lds((gas_u32*)g, (las_u32*)l, 16, 0, 0);
}

// ---------------- x -> bf16 ----------------
__global__ __launch_bounds__(256) void cvtx(const float* __restrict__ in,
                                            u16* __restrict__ out) {
  const size_t i = ((size_t)blockIdx.x * 256 + threadIdx.x) * 8;
  const float4 a = *(const float4*)(in + i);
  const float4 b = *(const float4*)(in + i + 4);
  alignas(16) u16 t[8] = {f2bf(a.x), f2bf(a.y), f2bf(a.z), f2bf(a.w),
                          f2bf(b.x), f2bf(b.y), f2bf(b.z), f2bf(b.w)};
  *(s8v*)(out + i) = *(const s8v*)t;
}

// ---------------- W [K][N] fp32 -> W^T [N][K] bf16 ----------------
__global__ __launch_bounds__(256) void wtrans(
    const float* __restrict__ w0, const float* __restrict__ w1,
    const float* __restrict__ w2, const float* __restrict__ w3,
    u16* __restrict__ o0, u16* __restrict__ o1, u16* __restrict__ o2,
    u16* __restrict__ o3) {
  const float* W;
  u16* O;
  switch (blockIdx.z) {
    case 0: W = w0; O = o0; break;
    case 1: W = w1; O = o1; break;
    case 2: W = w2; O = o2; break;
    default: W = w3; O = o3; break;
  }
  __shared__ float Tsh[64][65];
  const int tid = threadIdx.x;
  const int n0 = blockIdx.x * 64, k0 = blockIdx.y * 64;
  {
    const int rk = tid >> 2, c0 = (tid & 3) * 16;
#pragma unroll
    for (int u = 0; u < 4; ++u) {
      const float4 v = *(const float4*)&W[(size_t)(k0 + rk) * Cn + n0 + c0 + u * 4];
      Tsh[rk][c0 + u * 4 + 0] = v.x;
      Tsh[rk][c0 + u * 4 + 1] = v.y;
      Tsh[rk][c0 + u * 4 + 2] = v.z;
      Tsh[rk][c0 + u * 4 + 3] = v.w;
    }
  }
  __syncthreads();
  {
    const int rn = tid >> 2, ck0 = (tid & 3) * 16;
    alignas(16) u16 t[16];
#pragma unroll
    for (int u = 0; u < 16; ++u) t[u] = f2bf(Tsh[ck0 + u][rn]);
    *(s8v*)&O[(size_t)(n0 + rn) * Cn + k0 + ck0] = *(const s8v*)&t[0];
    *(s8v*)&O[(size_t)(n0 + rn) * Cn + k0 + ck0 + 8] = *(const s8v*)&t[8];
  }
}

// ---------------- GEMM body (m97 structure) ----------------
// OUT_MODE 0: bf16 [M][N]  1: V^T head-major  2: fp32 [M][N]
template <int OUT_MODE>
__device__ __forceinline__ void gemm_body(const u16* __restrict__ A,
                                          const u16* __restrict__ Bt,
                                          void* __restrict__ Cout, int bm,
                                          int bn, u16* As, u16* Bs) {
  const int N = Cn, K = Cn;
  const int tid = threadIdx.x;
  const int l = tid & 63, w = tid >> 6;
  const int lr = l & 15, lh = l >> 4;
  const int lrow = tid >> 2;
  const int lkcol = (tid & 3) * 8;
  const u16* Ag = A + (size_t)(bm * 128 + lrow) * K + lkcol;
  const u16* Bg = Bt + (size_t)(bn * 128 + lrow) * K + lkcol;
  const int wm = (w >> 1) * 64, wn = (w & 1) * 64;
  f4v acc[4][4] = {};
  for (int k0 = 0; k0 < K; k0 += 32) {
    __syncthreads();
    gl_lds16(Ag + k0, &As[(size_t)tid * 8]);
    gl_lds16(Ag + (size_t)64 * K + k0, &As[2048 + (size_t)tid * 8]);
    gl_lds16(Bg + k0, &Bs[(size_t)tid * 8]);
    gl_lds16(Bg + (size_t)64 * K + k0, &Bs[2048 + (size_t)tid * 8]);
    __syncthreads();
    s8v af[4], bfr[4];
#pragma unroll
    for (int i = 0; i < 4; ++i)
      af[i] = *(const s8v*)&As[(wm + i * 16 + lr) * 32 + lh * 8];
#pragma unroll
    for (int j = 0; j < 4; ++j)
      bfr[j] = *(const s8v*)&Bs[(wn + j * 16 + lr) * 32 + lh * 8];
    __builtin_amdgcn_s_setprio(1);
#pragma unroll
    for (int i = 0; i < 4; ++i)
#pragma unroll
      for (int j = 0; j < 4; ++j)
        acc[i][j] = mfma16(af[i], bfr[j], acc[i][j]);
    __builtin_amdgcn_s_setprio(0);
  }
  // D layout: col = lane&15, row = (lane>>4)*4 + reg  [m89]
  if (OUT_MODE == 2) {
    float* Cf = (float*)Cout;
#pragma unroll
    for (int i = 0; i < 4; ++i) {
      const int row = bm * 128 + wm + i * 16 + lh * 4;
#pragma unroll
      for (int j = 0; j < 4; ++j) {
        const int col = bn * 128 + wn + j * 16 + lr;
#pragma unroll
        for (int r = 0; r < 4; ++r)
          Cf[(size_t)(row + r) * N + col] = acc[i][j][r];
      }
    }
  } else if (OUT_MODE == 0) {
    u16* Cb = (u16*)Cout;
#pragma unroll
    for (int i = 0; i < 4; ++i) {
      const int row = bm * 128 + wm + i * 16 + lh * 4;
#pragma unroll
      for (int j = 0; j < 4; ++j) {
        const int col = bn * 128 + wn + j * 16 + lr;
#pragma unroll
        for (int r = 0; r < 4; ++r)
          Cb[(size_t)(row + r) * N + col] = f2bf(acc[i][j][r]);
      }
    }
  } else {
    // V^T head-major: Vt[((b*16+h)*64+d)][t]
    u16* Vt = (u16*)Cout;
#pragma unroll
    for (int i = 0; i < 4; ++i) {
      const int row0 = bm * 128 + wm + i * 16 + lh * 4;
      const int bq = row0 >> 11, t0 = row0 & 2047;
#pragma unroll
      for (int j = 0; j < 4; ++j) {
        const int col = bn * 128 + wn + j * 16 + lr;
        const int hh = col >> 6, dd = col & 63;
        alignas(8) u16 t4[4];
#pragma unroll
        for (int r = 0; r < 4; ++r) t4[r] = f2bf(acc[i][j][r]);
        *(s4v*)&Vt[((size_t)((bq * 16 + hh) * 64 + dd)) * Tn + t0] =
            *(const s4v*)t4;
      }
    }
  }
}

// Fused q/k/v projection: grid 1536 = 3 x (64 bm x 8 bn), XCD-swizzled.
__global__ __launch_bounds__(256) void gemm_qkv(
    const u16* __restrict__ A, const u16* __restrict__ btq,
    const u16* __restrict__ btk, const u16* __restrict__ btv,
    u16* __restrict__ qb, u16* __restrict__ kb, u16* __restrict__ vt) {
  __shared__ __align__(16) u16 As[4096], Bs[4096];
  const int bid = blockIdx.x;                   // 0..1535
  const int wg = (bid & 7) * 192 + (bid >> 3);  // bijective (1536 % 8 == 0)
  const int which = wg >> 9, inner = wg & 511;
  const int bm = inner & 63, bn = inner >> 6;
  if (which == 0)
    gemm_body<0>(A, btq, qb, bm, bn, As, Bs);
  else if (which == 1)
    gemm_body<0>(A, btk, kb, bm, bn, As, Bs);
  else
    gemm_body<1>(A, btv, vt, bm, bn, As, Bs);
}

template <int OUT_MODE>
__global__ __launch_bounds__(256) void gemm_bt(const u16* __restrict__ A,
                                               const u16* __restrict__ Bt,
                                               void* __restrict__ Cout) {
  __shared__ __align__(16) u16 As[4096], Bs[4096];
  const int bid = blockIdx.x;                 // 0..511
  const int wg = (bid & 7) * 64 + (bid >> 3);
  const int bm = wg & 63, bn = wg >> 6;
  gemm_body<OUT_MODE>(A, Bt, Cout, bm, bn, As, Bs);
}

// ---------------- Flash attention, 128x128 paired tiles ----------------
// LDS: Ks [128 k-rows][64 d] (8 chunks/row, chunk ^= row&7)
//      Vs [64 d-rows][128 t] (16 chunks/row, chunk ^= row&7)
//      Ps [128 q-rows][128 k] (16 chunks/row, chunk ^= row&7)
__device__ __forceinline__ void attn_step(const s8v* aq, const u16* Ks,
                                          const u16* Vs, u16* Ps, int w,
                                          int lr, int lh, bool diag, int k0,
                                          int q0, float* m_i, float* l_i,
                                          f4v* o) {
  const int sw = lr & 7;
  f4v s[8] = {};
  __builtin_amdgcn_s_setprio(1);
#pragma unroll
  for (int n = 0; n < 8; ++n) {
    const int rk = n * 16 + lr;
#pragma unroll
    for (int kd = 0; kd < 2; ++kd) {
      const s8v bk = *(const s8v*)&Ks[rk * 64 + (((kd * 4 + lh) ^ sw) * 8)];
      s[n] = mfma16(aq[kd], bk, s[n]);
    }
  }
  __builtin_amdgcn_s_setprio(0);
  // scale + causal mask (in place) + row max
  float rmv[4];
  bool okl = true;
#pragma unroll
  for (int r = 0; r < 4; ++r) {
    const int qglob = q0 + w * 16 + lh * 4 + r;
    float rm = -1e30f;
#pragma unroll
    for (int n = 0; n < 8; ++n) {
      float x = s[n][r] * 0.125f;  // 1/sqrt(64)
      if (diag && (k0 + n * 16 + lr > qglob)) x = -1e30f;
      s[n][r] = x;
      rm = fmaxf(rm, x);
    }
#pragma unroll
    for (int off = 1; off < 16; off <<= 1)
      rm = fmaxf(rm, __shfl_xor(rm, off, 16));
    rmv[r] = rm;
    okl = okl && (rm <= m_i[r] + 8.0f);
  }
  const bool skip = __all(okl);  // T13 defer-max, wave-uniform
#pragma unroll
  for (int r = 0; r < 4; ++r) {
    const int qrow_l = w * 16 + lh * 4 + r;
    if (!skip) {
      const float mnew = fmaxf(m_i[r], rmv[r]);
      const float alpha = __expf(m_i[r] - mnew);
      l_i[r] *= alpha;
#pragma unroll
      for (int n = 0; n < 4; ++n) o[n][r] *= alpha;
      m_i[r] = mnew;
    }
    const int swp = qrow_l & 7;
    float rs = 0.f;
#pragma unroll
    for (int n = 0; n < 8; ++n) {
      const float p = __expf(s[n][r] - m_i[r]);
      rs += p;
      const int col = n * 16 + lr;
      Ps[qrow_l * 128 + (((col >> 3) ^ swp) * 8) + (col & 7)] = f2bf(p);
    }
#pragma unroll
    for (int off = 1; off < 16; off <<= 1) rs += __shfl_xor(rs, off, 16);
    l_i[r] += rs;
  }
  // O += P V  (A = own P rows, B = V^T rows)
  {
    const int row = w * 16 + lr;
    s8v ap[4];
#pragma unroll
    for (int kh = 0; kh < 4; ++kh)
      ap[kh] = *(const s8v*)&Ps[row * 128 + (((kh * 4 + lh) ^ sw) * 8)];
    __builtin_amdgcn_s_setprio(1);
#pragma unroll
    for (int n = 0; n < 4; ++n) {
      const int rv = n * 16 + lr;
#pragma unroll
      for (int kh = 0; kh < 4; ++kh) {
        const s8v bv = *(const s8v*)&Vs[rv * 128 + (((kh * 4 + lh) ^ sw) * 8)];
        o[n] = mfma16(ap[kh], bv, o[n]);
      }
    }
    __builtin_amdgcn_s_setprio(0);
  }
}

// Block: paired 128-row q-tiles (xp, 15-xp) -> uniform 17 steps.
// Grid 512 (8 pairs x 64 bh), 512 threads = 8 waves, XCD-swizzled.
__global__ __launch_bounds__(512) void attn_big(const u16* __restrict__ qg,
                                                const u16* __restrict__ kg,
                                                const u16* __restrict__ vtg,
                                                u16* __restrict__ yg) {
  __shared__ __align__(16) u16 Ks[KVB * 64];   // 16 KB
  __shared__ __align__(16) u16 Vs[64 * KVB];   // 16 KB
  __shared__ __align__(16) u16 Ps[128 * KVB];  // 32 KB
  const int tid = threadIdx.x;
  const int l = tid & 63, w = tid >> 6;  // wave 0..7
  const int lr = l & 15, lh = l >> 4;
  const int bid = blockIdx.x;                  // 0..511
  const int wg = (bid & 7) * 64 + (bid >> 3);  // XCD chunking (512 % 8 == 0)
  const int bh = wg >> 3, xp = wg & 7;
  const int b = bh >> 4, h = bh & 15;
  const int tL = xp, tH = NT128 - 1 - xp;
  const int q0L = tL * 128, q0H = tH * 128;
  // Q-hoist: per-wave fragments in registers
  s8v aqL[2], aqH[2];
  {
    const int row = w * 16 + lr;
#pragma unroll
    for (int kd = 0; kd < 2; ++kd) {
      aqL[kd] = *(const s8v*)&qg[(size_t)(b * Tn + q0L + row) * Cn + h * 64 +
                                 kd * 32 + lh * 8];
      aqH[kd] = *(const s8v*)&qg[(size_t)(b * Tn + q0H + row) * Cn + h * 64 +
                                 kd * 32 + lh * 8];
    }
  }
  float mL[4] = {-1e30f, -1e30f, -1e30f, -1e30f}, lL[4] = {0.f, 0.f, 0.f, 0.f};
  float mH[4] = {-1e30f, -1e30f, -1e30f, -1e30f}, lH[4] = {0.f, 0.f, 0.f, 0.f};
  f4v oL[4] = {}, oH[4] = {};
  // reg prefetch (T14): K tile (128x64) and V^T tile (64x128), 2 s8v each
  const int krr0 = tid >> 3, krc = (tid & 7) * 8;    // K: rows 0..63 (+64)
  const int vrr0 = tid >> 4, vrc = (tid & 15) * 8;   // V: rows 0..31 (+32)
  s8v kr0, kr1, vr0, vr1;
  {
    kr0 = *(const s8v*)&kg[(size_t)(b * Tn + krr0) * Cn + h * 64 + krc];
    kr1 = *(const s8v*)&kg[(size_t)(b * Tn + 64 + krr0) * Cn + h * 64 + krc];
    vr0 = *(const s8v*)&vtg[((size_t)(bh * 64 + vrr0)) * Tn + vrc];
    vr1 = *(const s8v*)&vtg[((size_t)(bh * 64 + 32 + vrr0)) * Tn + vrc];
  }
  for (int kt = 0; kt <= tH; ++kt) {
    __syncthreads();  // all waves done reading Ks/Vs of kt-1
    {
      const int c = tid & 7;  // K logical chunk
      *(s8v*)&Ks[krr0 * 64 + ((c ^ (krr0 & 7)) * 8)] = kr0;
      *(s8v*)&Ks[(64 + krr0) * 64 + ((c ^ ((64 + krr0) & 7)) * 8)] = kr1;
      const int cv = tid & 15;  // V logical chunk
      *(s8v*)&Vs[vrr0 * 128 + ((cv ^ (vrr0 & 7)) * 8)] = vr0;
      *(s8v*)&Vs[(32 + vrr0) * 128 + ((cv ^ ((32 + vrr0) & 7)) * 8)] = vr1;
    }
    __syncthreads();
    if (kt < tH) {  // prefetch next tile; latency hides under compute
      const int k0n = (kt + 1) * KVB;
      kr0 = *(const s8v*)&kg[(size_t)(b * Tn + k0n + krr0) * Cn + h * 64 + krc];
      kr1 = *(const s8v*)&kg[(size_t)(b * Tn + k0n + 64 + krr0) * Cn + h * 64 + krc];
      vr0 = *(const s8v*)&vtg[((size_t)(bh * 64 + vrr0)) * Tn + k0n + vrc];
      vr1 = *(const s8v*)&vtg[((size_t)(bh * 64 + 32 + vrr0)) * Tn + k0n + vrc];
    }
    attn_step(aqH, Ks, Vs, Ps, w, lr, lh, kt == tH, kt * KVB, q0H, mH, lH, oH);
    if (kt <= tL)
      attn_step(aqL, Ks, Vs, Ps, w, lr, lh, kt == tL, kt * KVB, q0L, mL, lL,
                oL);
  }
#pragma unroll
  for (int r = 0; r < 4; ++r) {
    const float invH = 1.0f / lH[r];
    const float invL = 1.0f / lL[r];
    const int rowH = q0H + w * 16 + lh * 4 + r;
    const int rowL = q0L + w * 16 + lh * 4 + r;
#pragma unroll
    for (int n = 0; n < 4; ++n) {
      yg[(size_t)(b * Tn + rowH) * Cn + h * 64 + n * 16 + lr] =
          f2bf(oH[n][r] * invH);
      yg[(size_t)(b * Tn + rowL) * Cn + h * 64 + n * 16 + lr] =
          f2bf(oL[n][r] * invL);
    }
  }
}

}  // namespace

extern "C" void kernel_launch(void* const* d_in, const int* in_sizes, int n_in,
                              void* d_out, int out_size, void* d_ws,
                              size_t ws_size, hipStream_t stream) {
  (void)in_sizes; (void)n_in; (void)out_size; (void)ws_size;
  const float* x = (const float*)d_in[0];
  const float* Wk = (const float*)d_in[1];
  const float* Wq = (const float*)d_in[2];
  const float* Wv = (const float*)d_in[3];
  const float* Wp = (const float*)d_in[4];
  float* out = (float*)d_out;
  char* ws = (char*)d_ws;

  u16* xb = (u16*)(ws);                   // 16.8 MB
  u16* wqt = (u16*)(ws + 16777216);       // 2 MB each
  u16* wkt = (u16*)(ws + 18874368);
  u16* wvt = (u16*)(ws + 20971520);
  u16* wpt = (u16*)(ws + 23068672);
  u16* qb = (u16*)(ws + 25165824);        // 16.8 MB each
  u16* kb = (u16*)(ws + 41943040);
  u16* vt = (u16*)(ws + 58720256);        // head-major V^T [b][h][d][t]
  u16* yb = (u16*)(ws + 75497472);

  cvtx<<<dim3(4096), dim3(256), 0, stream>>>(x, xb);
  wtrans<<<dim3(16, 16, 4), dim3(256), 0, stream>>>(Wq, Wk, Wv, Wp, wqt, wkt,
                                                    wvt, wpt);
  gemm_qkv<<<dim3(1536), dim3(256), 0, stream>>>(xb, wqt, wkt, wvt, qb, kb,
                                                 vt);
  attn_big<<<dim3(512), dim3(512), 0, stream>>>(qb, kb, vt, yb);
  gemm_bt<2><<<dim3(512), dim3(256), 0, stream>>>(yb, wpt, out);
}

// Round 5
// 209.101 us; speedup vs baseline: 9.4420x; 1.0987x over previous
//
#include <hip/hip_runtime.h>
#include <cstddef>
#include <cstdint>

// CausalSelfAttention, bf16-MFMA pipeline, round 5.
// B=4, T=2048, C=1024, NH=16, HS=64.
//   cvtx:      x fp32 -> bf16
//   wtrans:    W fp32 [K][N] -> W^T bf16 [N][K]  (x4 weights)
//   gemm_qkv:  fused q/k/v projection (Q pre-scaled by 0.125*log2e)
//   gemm_bt<2>: output projection
//   attn_big:  flash attention; swapped QK^T (S^T via mfma(K,Q)) so softmax is
//              in-lane; PV via 16x16x16 MFMA with P staying in registers
//              (no P LDS round-trip); exp2-domain softmax; defer-max (T13);
//              reg-prefetch (T14); setprio (T5); XCD swizzle (T1).

namespace {

typedef unsigned short u16;
typedef unsigned int u32;
typedef __attribute__((ext_vector_type(8))) short s8v;   // 8 bf16 (4 VGPR)
typedef __attribute__((ext_vector_type(4))) short s4v;   // 4 bf16 (2 VGPR)
typedef __attribute__((ext_vector_type(4))) float f4v;

constexpr int Bn = 4, Tn = 2048, Cn = 1024;
constexpr int Mn = Bn * Tn;      // 8192
constexpr int KVB = 128;         // k-tile rows
constexpr int NT128 = Tn / 128;  // 16 tiles
constexpr float QSCALE = 0.125f * 1.44269504f;  // 1/sqrt(64) * log2(e)

__device__ __forceinline__ u16 bfc(float f) {  // fp32 -> bf16 (RNE, native)
  return __builtin_bit_cast(u16, (__bf16)f);
}

__device__ __forceinline__ f4v mfma16(s8v a, s8v b, f4v c) {
  return __builtin_amdgcn_mfma_f32_16x16x32_bf16(a, b, c, 0, 0, 0);
}

__device__ __forceinline__ f4v mfma16k16(s4v a, s4v b, f4v c) {
#if __has_builtin(__builtin_amdgcn_mfma_f32_16x16x16bf16_1k)
  return __builtin_amdgcn_mfma_f32_16x16x16bf16_1k(a, b, c, 0, 0, 0);
#else
  f4v d = c;
  asm("v_mfma_f32_16x16x16_bf16 %0, %1, %2, %0" : "+v"(d) : "v"(a), "v"(b));
  return d;
#endif
}

typedef __attribute__((address_space(1))) const u32 gas_u32;
typedef __attribute__((address_space(3))) u32 las_u32;
__device__ __forceinline__ void gl_lds16(const void* g, void* l) {
  __builtin_amdgcn_global_load_lds((gas_u32*)g, (las_u32*)l, 16, 0, 0);
}

// ---------------- x -> bf16 ----------------
__global__ __launch_bounds__(256) void cvtx(const float* __restrict__ in,
                                            u16* __restrict__ out) {
  const size_t i = ((size_t)blockIdx.x * 256 + threadIdx.x) * 8;
  const float4 a = *(const float4*)(in + i);
  const float4 b = *(const float4*)(in + i + 4);
  alignas(16) u16 t[8] = {bfc(a.x), bfc(a.y), bfc(a.z), bfc(a.w),
                          bfc(b.x), bfc(b.y), bfc(b.z), bfc(b.w)};
  *(s8v*)(out + i) = *(const s8v*)t;
}

// ---------------- W [K][N] fp32 -> W^T [N][K] bf16 ----------------
__global__ __launch_bounds__(256) void wtrans(
    const float* __restrict__ w0, const float* __restrict__ w1,
    const float* __restrict__ w2, const float* __restrict__ w3,
    u16* __restrict__ o0, u16* __restrict__ o1, u16* __restrict__ o2,
    u16* __restrict__ o3) {
  const float* W;
  u16* O;
  switch (blockIdx.z) {
    case 0: W = w0; O = o0; break;
    case 1: W = w1; O = o1; break;
    case 2: W = w2; O = o2; break;
    default: W = w3; O = o3; break;
  }
  __shared__ float Tsh[64][65];
  const int tid = threadIdx.x;
  const int n0 = blockIdx.x * 64, k0 = blockIdx.y * 64;
  {
    const int rk = tid >> 2, c0 = (tid & 3) * 16;
#pragma unroll
    for (int u = 0; u < 4; ++u) {
      const float4 v = *(const float4*)&W[(size_t)(k0 + rk) * Cn + n0 + c0 + u * 4];
      Tsh[rk][c0 + u * 4 + 0] = v.x;
      Tsh[rk][c0 + u * 4 + 1] = v.y;
      Tsh[rk][c0 + u * 4 + 2] = v.z;
      Tsh[rk][c0 + u * 4 + 3] = v.w;
    }
  }
  __syncthreads();
  {
    const int rn = tid >> 2, ck0 = (tid & 3) * 16;
    alignas(16) u16 t[16];
#pragma unroll
    for (int u = 0; u < 16; ++u) t[u] = bfc(Tsh[ck0 + u][rn]);
    *(s8v*)&O[(size_t)(n0 + rn) * Cn + k0 + ck0] = *(const s8v*)&t[0];
    *(s8v*)&O[(size_t)(n0 + rn) * Cn + k0 + ck0 + 8] = *(const s8v*)&t[8];
  }
}

// ---------------- GEMM body (m97 structure) ----------------
// OUT_MODE 0: bf16  1: V^T head-major  2: fp32  3: bf16 * QSCALE (for Q)
template <int OUT_MODE>
__device__ __forceinline__ void gemm_body(const u16* __restrict__ A,
                                          const u16* __restrict__ Bt,
                                          void* __restrict__ Cout, int bm,
                                          int bn, u16* As, u16* Bs) {
  const int N = Cn, K = Cn;
  const int tid = threadIdx.x;
  const int l = tid & 63, w = tid >> 6;
  const int lr = l & 15, lh = l >> 4;
  const int lrow = tid >> 2;
  const int lkcol = (tid & 3) * 8;
  const u16* Ag = A + (size_t)(bm * 128 + lrow) * K + lkcol;
  const u16* Bg = Bt + (size_t)(bn * 128 + lrow) * K + lkcol;
  const int wm = (w >> 1) * 64, wn = (w & 1) * 64;
  f4v acc[4][4] = {};
  for (int k0 = 0; k0 < K; k0 += 32) {
    __syncthreads();
    gl_lds16(Ag + k0, &As[(size_t)tid * 8]);
    gl_lds16(Ag + (size_t)64 * K + k0, &As[2048 + (size_t)tid * 8]);
    gl_lds16(Bg + k0, &Bs[(size_t)tid * 8]);
    gl_lds16(Bg + (size_t)64 * K + k0, &Bs[2048 + (size_t)tid * 8]);
    __syncthreads();
    s8v af[4], bfr[4];
#pragma unroll
    for (int i = 0; i < 4; ++i)
      af[i] = *(const s8v*)&As[(wm + i * 16 + lr) * 32 + lh * 8];
#pragma unroll
    for (int j = 0; j < 4; ++j)
      bfr[j] = *(const s8v*)&Bs[(wn + j * 16 + lr) * 32 + lh * 8];
    __builtin_amdgcn_s_setprio(1);
#pragma unroll
    for (int i = 0; i < 4; ++i)
#pragma unroll
      for (int j = 0; j < 4; ++j)
        acc[i][j] = mfma16(af[i], bfr[j], acc[i][j]);
    __builtin_amdgcn_s_setprio(0);
  }
  // D layout: col = lane&15, row = (lane>>4)*4 + reg  [m89]
  if (OUT_MODE == 2) {
    float* Cf = (float*)Cout;
#pragma unroll
    for (int i = 0; i < 4; ++i) {
      const int row = bm * 128 + wm + i * 16 + lh * 4;
#pragma unroll
      for (int j = 0; j < 4; ++j) {
        const int col = bn * 128 + wn + j * 16 + lr;
#pragma unroll
        for (int r = 0; r < 4; ++r)
          Cf[(size_t)(row + r) * N + col] = acc[i][j][r];
      }
    }
  } else if (OUT_MODE == 0 || OUT_MODE == 3) {
    u16* Cb = (u16*)Cout;
    const float sc = (OUT_MODE == 3) ? QSCALE : 1.0f;
#pragma unroll
    for (int i = 0; i < 4; ++i) {
      const int row = bm * 128 + wm + i * 16 + lh * 4;
#pragma unroll
      for (int j = 0; j < 4; ++j) {
        const int col = bn * 128 + wn + j * 16 + lr;
#pragma unroll
        for (int r = 0; r < 4; ++r)
          Cb[(size_t)(row + r) * N + col] = bfc(acc[i][j][r] * sc);
      }
    }
  } else {
    // V^T head-major: Vt[((b*16+h)*64+d)][t]
    u16* Vt = (u16*)Cout;
#pragma unroll
    for (int i = 0; i < 4; ++i) {
      const int row0 = bm * 128 + wm + i * 16 + lh * 4;
      const int bq = row0 >> 11, t0 = row0 & 2047;
#pragma unroll
      for (int j = 0; j < 4; ++j) {
        const int col = bn * 128 + wn + j * 16 + lr;
        const int hh = col >> 6, dd = col & 63;
        alignas(8) u16 t4[4];
#pragma unroll
        for (int r = 0; r < 4; ++r) t4[r] = bfc(acc[i][j][r]);
        *(s4v*)&Vt[((size_t)((bq * 16 + hh) * 64 + dd)) * Tn + t0] =
            *(const s4v*)t4;
      }
    }
  }
}

// Fused q/k/v projection: grid 1536 = 3 x (64 bm x 8 bn), XCD-swizzled.
__global__ __launch_bounds__(256) void gemm_qkv(
    const u16* __restrict__ A, const u16* __restrict__ btq,
    const u16* __restrict__ btk, const u16* __restrict__ btv,
    u16* __restrict__ qb, u16* __restrict__ kb, u16* __restrict__ vt) {
  __shared__ __align__(16) u16 As[4096], Bs[4096];
  const int bid = blockIdx.x;                   // 0..1535
  const int wg = (bid & 7) * 192 + (bid >> 3);  // bijective (1536 % 8 == 0)
  const int which = wg >> 9, inner = wg & 511;
  const int bm = inner & 63, bn = inner >> 6;
  if (which == 0)
    gemm_body<3>(A, btq, qb, bm, bn, As, Bs);   // Q pre-scaled
  else if (which == 1)
    gemm_body<0>(A, btk, kb, bm, bn, As, Bs);
  else
    gemm_body<1>(A, btv, vt, bm, bn, As, Bs);
}

template <int OUT_MODE>
__global__ __launch_bounds__(256) void gemm_bt(const u16* __restrict__ A,
                                               const u16* __restrict__ Bt,
                                               void* __restrict__ Cout) {
  __shared__ __align__(16) u16 As[4096], Bs[4096];
  const int bid = blockIdx.x;                 // 0..511
  const int wg = (bid & 7) * 64 + (bid >> 3);
  const int bm = wg & 63, bn = wg >> 6;
  gemm_body<OUT_MODE>(A, Bt, Cout, bm, bn, As, Bs);
}

// ---------------- Flash attention, swapped-QK^T ----------------
// S^T = mfma(K_frag, Q_frag): lane holds P[q = lane&15][k = n*16+lh*4+r].
// Softmax in-lane (+2 wave shuffles). P stays in registers as the exact
// A-fragment of mfma_16x16x16 for PV. m/l are per-lane scalars (q = lr).
__device__ __forceinline__ void attn_step(const s8v* aq, const u16* Ks,
                                          const u16* Vs, int ln, int w,
                                          int lr, int lh, bool diag, int k0,
                                          int q0, float& m_i, float& l_i,
                                          f4v* o) {
  f4v s[8] = {};
  {
    const int sw = lr & 7;
    __builtin_amdgcn_s_setprio(1);
#pragma unroll
    for (int n = 0; n < 8; ++n) {
      const int rk = n * 16 + lr;
#pragma unroll
      for (int kd = 0; kd < 2; ++kd) {
        const s8v bk = *(const s8v*)&Ks[rk * 64 + (((kd * 4 + lh) ^ sw) * 8)];
        s[n] = mfma16(bk, aq[kd], s[n]);  // SWAPPED: S^T[k][q]
      }
    }
    __builtin_amdgcn_s_setprio(0);
  }
  const int qg = q0 + w * 16 + lr;
  float rm = -1e30f;
  if (diag) {
#pragma unroll
    for (int n = 0; n < 8; ++n)
#pragma unroll
      for (int r = 0; r < 4; ++r) {
        float x = s[n][r];
        if (k0 + n * 16 + lh * 4 + r > qg) x = -1e30f;
        s[n][r] = x;
        rm = fmaxf(rm, x);
      }
  } else {
#pragma unroll
    for (int n = 0; n < 8; ++n)
#pragma unroll
      for (int r = 0; r < 4; ++r) rm = fmaxf(rm, s[n][r]);
  }
  rm = fmaxf(rm, __shfl_xor(rm, 16));
  rm = fmaxf(rm, __shfl_xor(rm, 32));
  if (!__all(rm <= m_i + 11.5f)) {  // T13 defer-max (log2 units)
    const float mnew = fmaxf(m_i, rm);
    const float al = exp2f(m_i - mnew);
    m_i = mnew;
    l_i *= al;
#pragma unroll
    for (int r = 0; r < 4; ++r) {
      const float ar = __shfl(al, (ln & 48) | (lh * 4 + r));
#pragma unroll
      for (int n2 = 0; n2 < 4; ++n2) o[n2][r] *= ar;
    }
  }
  float rs = 0.f;
#pragma unroll
  for (int n = 0; n < 8; ++n) {
    const float p0 = exp2f(s[n][0] - m_i);
    const float p1 = exp2f(s[n][1] - m_i);
    const float p2 = exp2f(s[n][2] - m_i);
    const float p3 = exp2f(s[n][3] - m_i);
    rs += (p0 + p1) + (p2 + p3);
    const s4v pa = {(short)bfc(p0), (short)bfc(p1), (short)bfc(p2),
                    (short)bfc(p3)};
    __builtin_amdgcn_s_setprio(1);
#pragma unroll
    for (int n2 = 0; n2 < 4; ++n2) {
      const int d = n2 * 16 + lr;
      const int cl = (2 * n + (lh >> 1)) ^ (lr & 7);
      const s4v bv = *(const s4v*)&Vs[d * 128 + cl * 8 + (lh & 1) * 4];
      o[n2] = mfma16k16(pa, bv, o[n2]);  // O[q=lh*4+reg][d=n2*16+lr]
    }
    __builtin_amdgcn_s_setprio(0);
  }
  rs += __shfl_xor(rs, 16);
  rs += __shfl_xor(rs, 32);
  l_i += rs;
}

// Block: paired 128-row q-tiles (xp, 15-xp) -> uniform 17 steps.
// Grid 512 (8 pairs x 64 bh), 512 threads = 8 waves, XCD-swizzled.
__global__ __launch_bounds__(512) void attn_big(const u16* __restrict__ qg,
                                                const u16* __restrict__ kg,
                                                const u16* __restrict__ vtg,
                                                u16* __restrict__ yg) {
  __shared__ __align__(16) u16 Ks[KVB * 64];  // 16 KB
  __shared__ __align__(16) u16 Vs[64 * KVB];  // 16 KB (V^T rows [d][t])
  const int tid = threadIdx.x;
  const int ln = tid & 63, w = tid >> 6;  // wave 0..7
  const int lr = ln & 15, lh = ln >> 4;
  const int bid = blockIdx.x;                  // 0..511
  const int wg = (bid & 7) * 64 + (bid >> 3);  // XCD chunking (512 % 8 == 0)
  const int bh = wg >> 3, xp = wg & 7;
  const int b = bh >> 4, h = bh & 15;
  const int tL = xp, tH = NT128 - 1 - xp;
  const int q0L = tL * 128, q0H = tH * 128;
  // Q-hoist: per-wave B-fragments in registers (Q already * QSCALE)
  s8v aqL[2], aqH[2];
  {
    const int row = w * 16 + lr;
#pragma unroll
    for (int kd = 0; kd < 2; ++kd) {
      aqL[kd] = *(const s8v*)&qg[(size_t)(b * Tn + q0L + row) * Cn + h * 64 +
                                 kd * 32 + lh * 8];
      aqH[kd] = *(const s8v*)&qg[(size_t)(b * Tn + q0H + row) * Cn + h * 64 +
                                 kd * 32 + lh * 8];
    }
  }
  float mL = -1e30f, lL = 0.f, mH = -1e30f, lH = 0.f;
  f4v oL[4] = {}, oH[4] = {};
  // reg prefetch (T14): K tile (128x64) and V^T tile (64x128), 2 s8v each
  const int krr0 = tid >> 3, krc = (tid & 7) * 8;   // K: rows 0..63 (+64)
  const int vrr0 = tid >> 4, vrc = (tid & 15) * 8;  // V: rows 0..31 (+32)
  s8v kr0, kr1, vr0, vr1;
  {
    kr0 = *(const s8v*)&kg[(size_t)(b * Tn + krr0) * Cn + h * 64 + krc];
    kr1 = *(const s8v*)&kg[(size_t)(b * Tn + 64 + krr0) * Cn + h * 64 + krc];
    vr0 = *(const s8v*)&vtg[((size_t)(bh * 64 + vrr0)) * Tn + vrc];
    vr1 = *(const s8v*)&vtg[((size_t)(bh * 64 + 32 + vrr0)) * Tn + vrc];
  }
  for (int kt = 0; kt <= tH; ++kt) {
    __syncthreads();  // all waves done reading Ks/Vs of kt-1
    {
      const int c = tid & 7;  // K logical chunk
      *(s8v*)&Ks[krr0 * 64 + ((c ^ (krr0 & 7)) * 8)] = kr0;
      *(s8v*)&Ks[(64 + krr0) * 64 + ((c ^ ((64 + krr0) & 7)) * 8)] = kr1;
      const int cv = tid & 15;  // V logical chunk
      *(s8v*)&Vs[vrr0 * 128 + ((cv ^ (vrr0 & 7)) * 8)] = vr0;
      *(s8v*)&Vs[(32 + vrr0) * 128 + ((cv ^ ((32 + vrr0) & 7)) * 8)] = vr1;
    }
    __syncthreads();
    if (kt < tH) {  // prefetch next tile; latency hides under compute
      const int k0n = (kt + 1) * KVB;
      kr0 = *(const s8v*)&kg[(size_t)(b * Tn + k0n + krr0) * Cn + h * 64 + krc];
      kr1 = *(const s8v*)&kg[(size_t)(b * Tn + k0n + 64 + krr0) * Cn + h * 64 + krc];
      vr0 = *(const s8v*)&vtg[((size_t)(bh * 64 + vrr0)) * Tn + k0n + vrc];
      vr1 = *(const s8v*)&vtg[((size_t)(bh * 64 + 32 + vrr0)) * Tn + k0n + vrc];
    }
    attn_step(aqH, Ks, Vs, ln, w, lr, lh, kt == tH, kt * KVB, q0H, mH, lH, oH);
    if (kt <= tL)
      attn_step(aqL, Ks, Vs, ln, w, lr, lh, kt == tL, kt * KVB, q0L, mL, lL,
                oL);
  }
  {
    const float linv = 1.0f / lH;
#pragma unroll
    for (int r = 0; r < 4; ++r) {
      const float iv = __shfl(linv, (ln & 48) | (lh * 4 + r));
      const int row = q0H + w * 16 + lh * 4 + r;
#pragma unroll
      for (int n2 = 0; n2 < 4; ++n2)
        yg[(size_t)(b * Tn + row) * Cn + h * 64 + n2 * 16 + lr] =
            bfc(oH[n2][r] * iv);
    }
  }
  {
    const float linv = 1.0f / lL;
#pragma unroll
    for (int r = 0; r < 4; ++r) {
      const float iv = __shfl(linv, (ln & 48) | (lh * 4 + r));
      const int row = q0L + w * 16 + lh * 4 + r;
#pragma unroll
      for (int n2 = 0; n2 < 4; ++n2)
        yg[(size_t)(b * Tn + row) * Cn + h * 64 + n2 * 16 + lr] =
            bfc(oL[n2][r] * iv);
    }
  }
}

}  // namespace

extern "C" void kernel_launch(void* const* d_in, const int* in_sizes, int n_in,
                              void* d_out, int out_size, void* d_ws,
                              size_t ws_size, hipStream_t stream) {
  (void)in_sizes; (void)n_in; (void)out_size; (void)ws_size;
  const float* x = (const float*)d_in[0];
  const float* Wk = (const float*)d_in[1];
  const float* Wq = (const float*)d_in[2];
  const float* Wv = (const float*)d_in[3];
  const float* Wp = (const float*)d_in[4];
  float* out = (float*)d_out;
  char* ws = (char*)d_ws;

  u16* xb = (u16*)(ws);              // 16.8 MB
  u16* wqt = (u16*)(ws + 16777216);  // 2 MB each
  u16* wkt = (u16*)(ws + 18874368);
  u16* wvt = (u16*)(ws + 20971520);
  u16* wpt = (u16*)(ws + 23068672);
  u16* qb = (u16*)(ws + 25165824);  // 16.8 MB each
  u16* kb = (u16*)(ws + 41943040);
  u16* vt = (u16*)(ws + 58720256);  // head-major V^T [b][h][d][t]
  u16* yb = (u16*)(ws + 75497472);

  cvtx<<<dim3(4096), dim3(256), 0, stream>>>(x, xb);
  wtrans<<<dim3(16, 16, 4), dim3(256), 0, stream>>>(Wq, Wk, Wv, Wp, wqt, wkt,
                                                    wvt, wpt);
  gemm_qkv<<<dim3(1536), dim3(256), 0, stream>>>(xb, wqt, wkt, wvt, qb, kb,
                                                 vt);
  attn_big<<<dim3(512), dim3(512), 0, stream>>>(qb, kb, vt, yb);
  gemm_bt<2><<<dim3(512), dim3(256), 0, stream>>>(yb, wpt, out);
}